// Round 17
// baseline (601.416 us; speedup 1.0000x reference)
//
#include <hip/hip_runtime.h>
#include <math.h>

// SCNN fused, round 17: r16 (515us) with GEMM2 B-fragments REGISTER-RESIDENT
// (48 VGPRs, loaded once from ws) instead of re-read from LDS per tile
// (12 b128 reads x 30 tiles on the MFMA-dependent path). Budget: 84+48=132
// <= ~170 at 3 waves/EU. p2 LDS staging removed (LDS back to 32.8KB).

typedef _Float16 half_t;
typedef _Float16 f16x8 __attribute__((ext_vector_type(8)));
typedef _Float16 f16x4 __attribute__((ext_vector_type(4)));
typedef __fp16 h2 __attribute__((ext_vector_type(2)));
typedef float f32x4 __attribute__((ext_vector_type(4)));
typedef unsigned int u32;

#define PRB 272    // bytes per pair-row: 64 c * 4B + 16 slack; conflict-free rows
#define NPAIRS 120 // 240 logical rows
#define ACTB (NPAIRS * PRB)  // 32640 B
#define E1R 128
#define E2R 144
#define E3R 176

// ws layout (u32): [0,3584) A1 frags, [3584,6656) sft frag-pairs (16x16x16),
// [6656, +64000) sconv A-frags
#define WS_FRAG_U32 6656
#define WS_AFRAG_U32 64000
#define WS_NEEDED ((WS_FRAG_U32 + WS_AFRAG_U32) * 4)

__device__ __host__ __forceinline__ constexpr int l_of(int c) {
  return (c >= 1) + (c >= 6) + (c >= 15) + (c >= 28);
}
__device__ __forceinline__ float lfac_of(int l) {
  return sqrtf(3.14159265358979323846f / (float)(4 * l + 1));
}
__device__ __forceinline__ u32 pk2(float a, float b) {
  auto v = __builtin_amdgcn_cvt_pkrtz(a, b);
  return __builtin_bit_cast(u32, v);
}
__device__ __forceinline__ u32 pk2rne(float a, float b) {
  unsigned short lo = __builtin_bit_cast(unsigned short, (half_t)a);
  unsigned short hi = __builtin_bit_cast(unsigned short, (half_t)b);
  return (u32)lo | ((u32)hi << 16);
}
__device__ __forceinline__ u32 pkrelu(float a, float b) {
#if defined(__has_builtin) && __has_builtin(__builtin_elementwise_max)
  u32 v = pk2(a, b);
  h2 hv = __builtin_bit_cast(h2, v);
  h2 z = {};
  hv = __builtin_elementwise_max(hv, z);
  return __builtin_bit_cast(u32, hv);
#else
  return pk2(fmaxf(a, 0.f), fmaxf(b, 0.f));
#endif
}
__device__ __forceinline__ float dot2(u32 xp, u32 wp, float acc) {
#if __has_builtin(__builtin_amdgcn_fdot2)
  return __builtin_amdgcn_fdot2(__builtin_bit_cast(h2, xp), __builtin_bit_cast(h2, wp), acc, false);
#else
  h2 xv = __builtin_bit_cast(h2, xp), wv = __builtin_bit_cast(h2, wp);
  return acc + (float)xv[0] * (float)wv[0] + (float)xv[1] * (float)wv[1];
#endif
}
__device__ __forceinline__ u32 mergepair(u32 a, u32 b, int par) {
  return par ? ((a >> 16) | (b & 0xffff0000u))
             : ((a & 0x0000ffffu) | (b << 16));
}
__device__ __forceinline__ f32x4 mfma16(f16x8 a, f16x8 b, f32x4 c) {
  return __builtin_amdgcn_mfma_f32_16x16x32_f16(a, b, c, 0, 0, 0);
}
__device__ __forceinline__ f32x4 mfma16x16(f16x4 a, f16x4 b, f32x4 c) {
  return __builtin_amdgcn_mfma_f32_16x16x16f16(a, b, c, 0, 0, 0);
}

struct Frags {
  f16x8 a1[7][2];     // isft: d = 16*mt + (l&15), k=c = 32*kt + 8*(l>>4) + j (0 pad)
  f16x4 a2A[3][4];    // sft GEMM2 B-frags, kt = 2q   (n=c, k=d convention)
  f16x4 a2B[3][4];    // sft GEMM2 B-frags, kt = 2q+1
};

__device__ __forceinline__ f16x8 ldpair8(const char* base, int par) {
  const uint4 q0 = *(const uint4*)(base);
  const uint4 q1 = *(const uint4*)(base + 16);
  uint4 r;
  r.x = mergepair(q0.x, q0.y, par);
  r.y = mergepair(q0.z, q0.w, par);
  r.z = mergepair(q1.x, q1.y, par);
  r.w = mergepair(q1.z, q1.w, par);
  return __builtin_bit_cast(f16x8, r);
}

// ---------------- nonlin: GEMM1 (16x16x32) -> relu/pack -> GEMM2 (16x16x16,
// A = packed Y verbatim (m=r,k=d), B = resident sft frag (n=c,k=d) -> D[r,c]
__device__ void nonlin_tiles(const Frags& F, char* smem, int lane, int wid,
                             int T, int TA, int inArow, int inBrow,
                             int outArow, int outBrow) {
  const int i15 = lane & 15, g = lane >> 4;
  for (int t = wid; t < T; t += 4) {
    const int inrow = (t < TA) ? (inArow + t * 16) : (inBrow + (t - TA) * 16);
    const int outrow = (t < TA) ? (outArow + t * 16) : (outBrow + (t - TA) * 16);
    const int R = inrow + i15, par = R & 1;
    const char* ib = smem + (R >> 1) * PRB + g * 32;
    f16x8 b0 = ldpair8(ib, par);
    f16x8 b1 = ldpair8(ib + 128, par);
    f32x4 acc1[7];
#pragma unroll
    for (int mt = 0; mt < 7; ++mt) {
      f32x4 z = {0.f, 0.f, 0.f, 0.f};
      z = mfma16(F.a1[mt][0], b0, z);
      acc1[mt] = mfma16(F.a1[mt][1], b1, z);
    }
    // relu + pack: pk[kt] = Y[d = 16kt + 4g + j, r = i15] as 4 fp16 (2 dwords)
    u32 pk[7][2];
#pragma unroll
    for (int kt = 0; kt < 7; ++kt) {
      pk[kt][0] = pkrelu(acc1[kt][0], acc1[kt][1]);
      pk[kt][1] = pkrelu(acc1[kt][2], acc1[kt][3]);
    }
    // GEMM2: A = pk (m=r, k=d), B = resident frag (n=c, k=d) -> D[r, c]
    f32x4 acc2[3];
#pragma unroll
    for (int n = 0; n < 3; ++n) acc2[n] = (f32x4){0.f, 0.f, 0.f, 0.f};
#pragma unroll
    for (int q = 0; q < 4; ++q) {
      uint2 yw0; yw0.x = pk[2 * q][0]; yw0.y = pk[2 * q][1];
      const f16x4 yA = __builtin_bit_cast(f16x4, yw0);
      f16x4 yB = {};
      if (q < 3) {
        uint2 yw1; yw1.x = pk[2 * q + 1][0]; yw1.y = pk[2 * q + 1][1];
        yB = __builtin_bit_cast(f16x4, yw1);
      }
#pragma unroll
      for (int n = 0; n < 3; ++n) {
        acc2[n] = mfma16x16(yA, F.a2A[n][q], acc2[n]);
        if (q < 3) acc2[n] = mfma16x16(yB, F.a2B[n][q], acc2[n]);
      }
    }
    // write: lane owns col c = 16n + i15, rows outrow + 4g + {0..3}. Full dwords.
    char* ob = smem + ((outrow >> 1) + 2 * g) * PRB + i15 * 4;
#pragma unroll
    for (int n = 0; n < 3; ++n) {
      *(u32*)(ob + n * 64) = pk2(acc2[n][0], acc2[n][1]);
      *(u32*)(ob + PRB + n * 64) = pk2(acc2[n][2], acc2[n][3]);
    }
  }
}

// ---------------- sconv via MFMA (unchanged from r9/r11/r13/r16)
template <int O, int I, int SPL, bool INPLACE>
__device__ void sconv_mfma(const uint4* __restrict__ afr, char* smem,
                           int lane, int wid, int inArow, int inBrow, int outrow) {
  constexpr int Mt = O / 16;
  constexpr int Kt = (I + 31) / 32;
  constexpr int CELLS = Mt * 6;
  constexpr int NCI = (CELLS + 3) / 4;
  constexpr bool CONCAT = (SPL < I);
  const int n15 = lane & 15, g = lane >> 4;

  f32x4 accs[INPLACE ? NCI : 1];

#pragma unroll
  for (int ci = 0; ci < NCI; ++ci) {
    const int cell = wid + 4 * ci;
    if (cell < CELLS) {
      const int mt = cell / 6, grp = cell - 6 * mt;
      const int l = (grp >= 1) + (grp >= 2) + (grp >= 3) + (grp >= 4);
      const int c0 = l * (2 * l - 1) + ((grp == 5) ? 16 : 0);
      const int c = c0 + n15;
      f32x4 acc = {0.f, 0.f, 0.f, 0.f};
#pragma unroll
      for (int kt = 0; kt < Kt; ++kt) {
        const f16x8 A = __builtin_bit_cast(f16x8, afr[((l * Mt + mt) * Kt + kt) * 64 + lane]);
        int basepair;
        if constexpr (CONCAT) {
          const int iA0 = 32 * kt + 8 * g;
          basepair = ((iA0 < SPL) ? (inArow + iA0) : (inBrow + iA0 - SPL)) >> 1;
        } else {
          basepair = (inArow >> 1) + 16 * kt + 4 * g;
        }
        const char* bp = smem + basepair * PRB + c * 4;
        uint4 b4;
        b4.x = *(const u32*)(bp);
        b4.y = *(const u32*)(bp + PRB);
        b4.z = *(const u32*)(bp + 2 * PRB);
        b4.w = *(const u32*)(bp + 3 * PRB);
        acc = mfma16(A, __builtin_bit_cast(f16x8, b4), acc);
      }
      if constexpr (INPLACE) {
        accs[ci] = acc;
      } else {
        const int sz = (grp == 4) ? 16 : (((grp == 0) || (grp == 5)) ? 1 : (4 * l + 1));
        if (n15 < sz) {
          char* wb = smem + ((outrow >> 1) + 8 * mt + 2 * g) * PRB + c * 4;
          *(u32*)(wb) = pk2(acc[0], acc[1]);
          *(u32*)(wb + PRB) = pk2(acc[2], acc[3]);
        }
      }
    }
  }
  if constexpr (INPLACE) {
    __syncthreads();
#pragma unroll
    for (int ci = 0; ci < NCI; ++ci) {
      const int cell = wid + 4 * ci;
      if (cell < CELLS) {
        const int mt = cell / 6, grp = cell - 6 * mt;
        const int l = (grp >= 1) + (grp >= 2) + (grp >= 3) + (grp >= 4);
        const int c0 = l * (2 * l - 1) + ((grp == 5) ? 16 : 0);
        const int sz = (grp == 4) ? 16 : (((grp == 0) || (grp == 5)) ? 1 : (4 * l + 1));
        const int c = c0 + n15;
        if (n15 < sz) {
          char* wb = smem + ((outrow >> 1) + 8 * mt + 2 * g) * PRB + c * 4;
          *(u32*)(wb) = pk2(accs[ci][0], accs[ci][1]);
          *(u32*)(wb + PRB) = pk2(accs[ci][2], accs[ci][3]);
        }
      }
    }
  }
  __syncthreads();
}

// ---------------- dot2 sconv (no-ws fallback only)
template <int O, int I, int SPL, int NSEG, int NIP, int SEG>
__device__ __forceinline__ void sconv_acc_p(const float* __restrict__ wf, int o, int ip,
                                            bool act, const char* smem, int inArow, int inBrow,
                                            float* acc) {
  constexpr int NC = 48 / NSEG;
  constexpr int NU4 = NC / 4;
  constexpr int C0 = SEG * NC;
#pragma unroll
  for (int k = 0; k < NC; ++k) acc[k] = 0.f;
  if (!act) return;
#pragma unroll 2
  for (int p = ip; p < I / 2; p += NIP) {
    const int rA = 2 * p;
    const char* rb = smem +
        (((rA < SPL) ? ((inArow >> 1) + p) : ((inBrow >> 1) + p - SPL / 2)) * PRB) + C0 * 4;
    u32 wv[5];
#pragma unroll
    for (int l = 0; l < 5; ++l)
      wv[l] = pk2rne(wf[(o * I + rA) * 5 + l], wf[(o * I + rA + 1) * 5 + l]);
#pragma unroll
    for (int k = 0; k < NU4; ++k) {
      const uint4 q = *(const uint4*)(rb + k * 16);
      const u32 qq[4] = {q.x, q.y, q.z, q.w};
#pragma unroll
      for (int j = 0; j < 4; ++j) {
        const int c = C0 + k * 4 + j;
        acc[k * 4 + j] = dot2(qq[j], wv[l_of(c)], acc[k * 4 + j]);
      }
    }
  }
}

template <int NSEG, int SEG>
__device__ __forceinline__ void sconv_write_p(char* smem, int outrow, int o, const float* acc) {
  constexpr int NC = 48 / NSEG;
  constexpr int C0 = SEG * NC;
  const int R = outrow + o;
  char* wb = smem + (R >> 1) * PRB + (R & 1) * 2 + C0 * 4;
#pragma unroll
  for (int k = 0; k < NC; ++k) {
    const int c = C0 + k;
    *(half_t*)(wb + k * 4) = (half_t)(acc[k] * lfac_of(l_of(c)));
  }
}

template <int O, int I, int SPL, int NSEG, int NIP>
__device__ void sconv_layer(const float* __restrict__ wf, char* smem, int tid,
                            int inArow, int inBrow, int outrow) {
  constexpr int NC = 48 / NSEG;
  const int ip = (NIP == 1) ? 0 : (tid % NIP);
  const int seg = (tid / NIP) % NSEG;
  const int o = tid / (NIP * NSEG);
  const bool act = (o < O);
  float acc[NC];
  if (seg == 0)
    sconv_acc_p<O, I, SPL, NSEG, NIP, 0>(wf, o, ip, act, smem, inArow, inBrow, acc);
  else if (seg == 1)
    sconv_acc_p<O, I, SPL, NSEG, NIP, 1>(wf, o, ip, act, smem, inArow, inBrow, acc);
  else if constexpr (NSEG > 2) {
    sconv_acc_p<O, I, SPL, NSEG, NIP, 2>(wf, o, ip, act, smem, inArow, inBrow, acc);
  }
  if constexpr (NIP >= 2) {
#pragma unroll
    for (int k = 0; k < NC; ++k) acc[k] += __shfl_xor(acc[k], 1);
  }
  if constexpr (NIP >= 4) {
#pragma unroll
    for (int k = 0; k < NC; ++k) acc[k] += __shfl_xor(acc[k], 2);
  }
  __syncthreads();
  if (act && ip == 0) {
    if (seg == 0) sconv_write_p<NSEG, 0>(smem, outrow, o, acc);
    else if (seg == 1) sconv_write_p<NSEG, 1>(smem, outrow, o, acc);
    else if constexpr (NSEG > 2) { sconv_write_p<NSEG, 2>(smem, outrow, o, acc); }
  }
  __syncthreads();
}

// ---------------- prep: bake nonlin frags + sconv A-frags into ws
__global__ void scnn_prep(const float* __restrict__ sft, const float* __restrict__ isft,
                          const float* __restrict__ w1, const float* __restrict__ w2,
                          const float* __restrict__ w3, const float* __restrict__ w4,
                          const float* __restrict__ w5, const float* __restrict__ w6,
                          const float* __restrict__ w7, const float* __restrict__ w8,
                          const float* __restrict__ w9, u32* __restrict__ wsbuf) {
  const int gid = blockIdx.x * 256 + threadIdx.x;
  if (gid < 3584) {  // A1 frags (isft), 16x16x32 convention
    const int f = gid >> 8, r = gid & 255, ln = r >> 2, wd = r & 3;
    const int mt = f >> 1, kt = f & 1;
    const int d = 16 * mt + (ln & 15);
    const int c = 32 * kt + 8 * (ln >> 4) + 2 * wd;
    const float v0 = (d < 100 && c < 45) ? isft[d * 45 + c] : 0.f;
    const float v1 = (d < 100 && c + 1 < 45) ? isft[d * 45 + c + 1] : 0.f;
    wsbuf[gid] = pk2rne(v0, v1);
  } else if (gid < WS_FRAG_U32) {  // sft frag-pairs, 16x16x16 convention
    const int e = gid - 3584;
    const int f = e >> 8, r = e & 255, ln = r >> 2, wd = r & 3;
    const int m = f >> 2, q = f & 3;
    const int kt = 2 * q + (wd >> 1);
    const int c = 16 * m + (ln & 15);
    const int d = 16 * kt + 4 * (ln >> 4) + 2 * (wd & 1);
    const float v0 = (kt < 7 && c < 45 && d < 100) ? sft[c * 100 + d] : 0.f;
    const float v1 = (kt < 7 && c < 45 && d + 1 < 100) ? sft[c * 100 + d + 1] : 0.f;
    wsbuf[gid] = pk2rne(v0, v1);
  } else if (gid < WS_FRAG_U32 + WS_AFRAG_U32) {  // sconv A-frags, lfac folded
    const int e = gid - WS_FRAG_U32;
    const int frag = e >> 8, r = e & 255, ln = r >> 2, wd = r & 3;
    const float* src; int O, I, Mt, Kt, off;
    if (frag < 5)        { src = w1; O = 16;  I = 4;   Mt = 1; Kt = 1; off = 0;   }
    else if (frag < 15)  { src = w2; O = 32;  I = 16;  Mt = 2; Kt = 1; off = 5;   }
    else if (frag < 35)  { src = w3; O = 64;  I = 32;  Mt = 4; Kt = 1; off = 15;  }
    else if (frag < 115) { src = w4; O = 128; I = 64;  Mt = 8; Kt = 2; off = 35;  }
    else if (frag < 195) { src = w5; O = 64;  I = 128; Mt = 4; Kt = 4; off = 115; }
    else if (frag < 235) { src = w6; O = 32;  I = 128; Mt = 2; Kt = 4; off = 195; }
    else if (frag < 245) { src = w7; O = 16;  I = 64;  Mt = 1; Kt = 2; off = 235; }
    else                 { src = w8; O = 16;  I = 32;  Mt = 1; Kt = 1; off = 245; }
    const int fl = frag - off;
    const int l = fl / (Mt * Kt), rem = fl % (Mt * Kt);
    const int mt = rem / Kt, kt = rem % Kt;
    const int o = 16 * mt + (ln & 15);
    const int i0 = 32 * kt + 8 * (ln >> 4) + 2 * wd;
    const float lf = lfac_of(l);
    const float v0 = (i0 < I) ? src[(o * I + i0) * 5 + l] * lf : 0.f;
    const float v1 = (i0 + 1 < I) ? src[(o * I + i0 + 1) * 5 + l] * lf : 0.f;
    wsbuf[gid] = pk2rne(v0, v1);
  }
  (void)w9;
}

// ---------------- main fused kernel
template <bool TW>
__global__ __launch_bounds__(256, 3) void scnn_mfma(
    const float* __restrict__ x, const float* __restrict__ sft, const float* __restrict__ isft,
    const float* __restrict__ w1, const float* __restrict__ w2, const float* __restrict__ w3,
    const float* __restrict__ w4, const float* __restrict__ w5, const float* __restrict__ w6,
    const float* __restrict__ w7, const float* __restrict__ w8, const float* __restrict__ w9,
    const u32* __restrict__ wsbuf, float* __restrict__ out) {
  __shared__ __align__(16) char smem[ACTB];
  const int tid = threadIdx.x, lane = tid & 63, wid = tid >> 6, b = blockIdx.x;
  const uint4* afrB = TW ? ((const uint4*)wsbuf) + (WS_FRAG_U32 / 4) : nullptr;

  Frags F;
  if constexpr (TW) {
    const uint4* p1 = (const uint4*)wsbuf;
#pragma unroll
    for (int f = 0; f < 14; ++f)
      F.a1[f / 2][f % 2] = __builtin_bit_cast(f16x8, p1[f * 64 + lane]);
    const uint4* p2g = p1 + 14 * 64;
#pragma unroll
    for (int f = 0; f < 12; ++f) {
      const uint4 aw = p2g[f * 64 + lane];
      uint2 lo; lo.x = aw.x; lo.y = aw.y;
      uint2 hi; hi.x = aw.z; hi.y = aw.w;
      F.a2A[f / 4][f % 4] = __builtin_bit_cast(f16x4, lo);
      F.a2B[f / 4][f % 4] = __builtin_bit_cast(f16x4, hi);
    }
  } else {
    const int i15 = lane & 15, g = lane >> 4;
#pragma unroll
    for (int mt = 0; mt < 7; ++mt)
#pragma unroll
      for (int kt = 0; kt < 2; ++kt) {
        const int d = 16 * mt + i15;
        f16x8 v;
#pragma unroll
        for (int j = 0; j < 8; ++j) {
          const int c = 32 * kt + 8 * g + j;
          v[j] = (half_t)((d < 100 && c < 45) ? isft[d * 45 + c] : 0.f);
        }
        F.a1[mt][kt] = v;
      }
#pragma unroll
    for (int n = 0; n < 3; ++n)
#pragma unroll
      for (int q = 0; q < 4; ++q) {
        const int c0 = 16 * n + i15;
        f16x4 vA, vB;
#pragma unroll
        for (int j = 0; j < 4; ++j) {
          const int dA = 32 * q + 4 * g + j;
          vA[j] = (half_t)((c0 < 45 && dA < 100) ? sft[c0 * 100 + dA] : 0.f);
          const int dB = 32 * q + 16 + 4 * g + j;
          vB[j] = (half_t)((c0 < 45 && dB < 100) ? sft[c0 * 100 + dB] : 0.f);
        }
        F.a2A[n][q] = vA;
        F.a2B[n][q] = vB;
      }
  }

  // zero the activation buffer (K-padded MFMA B-reads must see finite zeros)
  for (int idx = tid; idx < ACTB / 4; idx += 256)
    ((u32*)smem)[idx] = 0u;
  __syncthreads();
  // stage x [4,45] -> rows 0..3 (paired layout)
  if (tid < 192) {
    const int r = tid / 48, c = tid % 48;
    const float v = (c < 45) ? x[b * 180 + r * 45 + c] : 0.f;
    *(half_t*)(smem + (r >> 1) * PRB + c * 4 + (r & 1) * 2) = (half_t)v;
  }
  __syncthreads();

  if constexpr (TW) {
    sconv_mfma<16, 4, 4, true>(afrB + 0 * 64, smem, lane, wid, 0, 0, 0);
    nonlin_tiles(F, smem, lane, wid, 1, 1, 0, 0, E1R, E1R);
    __syncthreads();
    sconv_mfma<32, 16, 16, false>(afrB + 5 * 64, smem, lane, wid, E1R, E1R, 0);
    nonlin_tiles(F, smem, lane, wid, 2, 2, 0, 0, E2R, E2R);
    __syncthreads();
    sconv_mfma<64, 32, 32, false>(afrB + 15 * 64, smem, lane, wid, E2R, E2R, 0);
    nonlin_tiles(F, smem, lane, wid, 4, 4, 0, 0, E3R, E3R);
    __syncthreads();
    sconv_mfma<128, 64, 64, false>(afrB + 35 * 64, smem, lane, wid, E3R, E3R, 0);
    nonlin_tiles(F, smem, lane, wid, 8, 8, 0, 0, 0, 0);
    __syncthreads();
    sconv_mfma<64, 128, 128, true>(afrB + 115 * 64, smem, lane, wid, 0, 0, 0);
    nonlin_tiles(F, smem, lane, wid, 8, 4, 0, E3R, 0, E3R);
    __syncthreads();
    sconv_mfma<32, 128, 64, true>(afrB + 195 * 64, smem, lane, wid, 0, E3R, 0);
    nonlin_tiles(F, smem, lane, wid, 4, 2, 0, E2R, 0, E2R);
    __syncthreads();
    sconv_mfma<16, 64, 32, true>(afrB + 235 * 64, smem, lane, wid, 0, E2R, 0);
    nonlin_tiles(F, smem, lane, wid, 2, 1, 0, E1R, 0, E1R);
    __syncthreads();
    sconv_mfma<16, 32, 16, true>(afrB + 245 * 64, smem, lane, wid, 0, E1R, 0);
    nonlin_tiles(F, smem, lane, wid, 1, 1, 0, 0, 0, 0);
    __syncthreads();
  } else {
    sconv_layer<16, 4, 4, 3, 4>(w1, smem, tid, 0, 0, 0);
    nonlin_tiles(F, smem, lane, wid, 1, 1, 0, 0, E1R, E1R);
    __syncthreads();
    sconv_layer<32, 16, 16, 2, 4>(w2, smem, tid, E1R, E1R, 0);
    nonlin_tiles(F, smem, lane, wid, 2, 2, 0, 0, E2R, E2R);
    __syncthreads();
    sconv_layer<64, 32, 32, 2, 2>(w3, smem, tid, E2R, E2R, 0);
    nonlin_tiles(F, smem, lane, wid, 4, 4, 0, 0, E3R, E3R);
    __syncthreads();
    sconv_layer<128, 64, 64, 2, 1>(w4, smem, tid, E3R, E3R, 0);
    nonlin_tiles(F, smem, lane, wid, 8, 8, 0, 0, 0, 0);
    __syncthreads();
    sconv_layer<64, 128, 128, 2, 2>(w5, smem, tid, 0, 0, 0);
    nonlin_tiles(F, smem, lane, wid, 8, 4, 0, E3R, 0, E3R);
    __syncthreads();
    sconv_layer<32, 128, 64, 2, 4>(w6, smem, tid, 0, E3R, 0);
    nonlin_tiles(F, smem, lane, wid, 4, 2, 0, E2R, 0, E2R);
    __syncthreads();
    sconv_layer<16, 64, 32, 3, 4>(w7, smem, tid, 0, E2R, 0);
    nonlin_tiles(F, smem, lane, wid, 2, 1, 0, E1R, 0, E1R);
    __syncthreads();
    sconv_layer<16, 32, 16, 3, 4>(w8, smem, tid, 0, E1R, 0);
    nonlin_tiles(F, smem, lane, wid, 1, 1, 0, 0, 0, 0);
    __syncthreads();
  }

  // final sconv: O=1, I=16 (d4 rows 0..15) -> out[b,c] fp32
  if (tid < 45) {
    const int c = tid, l = l_of(c);
    float acc = 0.f;
#pragma unroll
    for (int i = 0; i < 16; ++i)
      acc += w9[i * 5 + l] *
             (float)(*(const half_t*)(smem + (i >> 1) * PRB + c * 4 + (i & 1) * 2));
    out[b * 45 + c] = acc * lfac_of(l);
  }
}

extern "C" void kernel_launch(void* const* d_in, const int* in_sizes, int n_in,
                              void* d_out, int out_size, void* d_ws, size_t ws_size,
                              hipStream_t stream) {
  (void)n_in; (void)out_size;
  const float* x    = (const float*)d_in[0];
  const float* sft  = (const float*)d_in[1];
  const float* isft = (const float*)d_in[2];
  const float* w1 = (const float*)d_in[3];
  const float* w2 = (const float*)d_in[4];
  const float* w3 = (const float*)d_in[5];
  const float* w4 = (const float*)d_in[6];
  const float* w5 = (const float*)d_in[7];
  const float* w6 = (const float*)d_in[8];
  const float* w7 = (const float*)d_in[9];
  const float* w8 = (const float*)d_in[10];
  const float* w9 = (const float*)d_in[11];
  float* out = (float*)d_out;

  const int batch = in_sizes[0] / 180;  // 16384

  if (ws_size >= (size_t)WS_NEEDED) {
    u32* wsbuf = (u32*)d_ws;
    const int prepN = WS_FRAG_U32 + WS_AFRAG_U32;
    hipLaunchKernelGGL(scnn_prep, dim3((prepN + 255) / 256), dim3(256), 0, stream,
                       sft, isft, w1, w2, w3, w4, w5, w6, w7, w8, w9, wsbuf);
    hipLaunchKernelGGL((scnn_mfma<true>), dim3(batch), dim3(256), 0, stream,
                       x, sft, isft, w1, w2, w3, w4, w5, w6, w7, w8, w9, wsbuf, out);
  } else {
    hipLaunchKernelGGL((scnn_mfma<false>), dim3(batch), dim3(256), 0, stream,
                       x, sft, isft, w1, w2, w3, w4, w5, w6, w7, w8, w9,
                       (const u32*)nullptr, out);
  }
}

// Round 18
// 515.172 us; speedup vs baseline: 1.1674x; 1.1674x over previous
//
#include <hip/hip_runtime.h>
#include <math.h>

// SCNN fused, round 18: REVERT to round-16 exactly (verified best: 515.6us,
// absmax 6.1e-5). r17's register-resident a2 failed: allocator kept VGPR=84
// and spilled the frags to scratch (FETCH/WRITE +12MB, dur +17%) -> LDS is
// the right home for the loop-invariant GEMM2 B-fragment table at this
// occupancy tier. Structure: 256 thr, (256,3), all-MFMA layers, p2 in LDS.

typedef _Float16 half_t;
typedef _Float16 f16x8 __attribute__((ext_vector_type(8)));
typedef _Float16 f16x4 __attribute__((ext_vector_type(4)));
typedef __fp16 h2 __attribute__((ext_vector_type(2)));
typedef float f32x4 __attribute__((ext_vector_type(4)));
typedef unsigned int u32;

#define PRB 272    // bytes per pair-row: 64 c * 4B + 16 slack; conflict-free rows
#define NPAIRS 120 // 240 logical rows
#define ACTB (NPAIRS * PRB)  // 32640 B
#define P2N 768    // p2 table: 12 frag-pairs * 64 lanes (uint4)
#define E1R 128
#define E2R 144
#define E3R 176

// ws layout (u32): [0,3584) A1 frags, [3584,6656) sft frag-pairs (16x16x16),
// [6656, +64000) sconv A-frags
#define WS_FRAG_U32 6656
#define WS_AFRAG_U32 64000
#define WS_NEEDED ((WS_FRAG_U32 + WS_AFRAG_U32) * 4)

__device__ __host__ __forceinline__ constexpr int l_of(int c) {
  return (c >= 1) + (c >= 6) + (c >= 15) + (c >= 28);
}
__device__ __forceinline__ float lfac_of(int l) {
  return sqrtf(3.14159265358979323846f / (float)(4 * l + 1));
}
__device__ __forceinline__ u32 pk2(float a, float b) {
  auto v = __builtin_amdgcn_cvt_pkrtz(a, b);
  return __builtin_bit_cast(u32, v);
}
__device__ __forceinline__ u32 pk2rne(float a, float b) {
  unsigned short lo = __builtin_bit_cast(unsigned short, (half_t)a);
  unsigned short hi = __builtin_bit_cast(unsigned short, (half_t)b);
  return (u32)lo | ((u32)hi << 16);
}
__device__ __forceinline__ u32 pkrelu(float a, float b) {
#if defined(__has_builtin) && __has_builtin(__builtin_elementwise_max)
  u32 v = pk2(a, b);
  h2 hv = __builtin_bit_cast(h2, v);
  h2 z = {};
  hv = __builtin_elementwise_max(hv, z);
  return __builtin_bit_cast(u32, hv);
#else
  return pk2(fmaxf(a, 0.f), fmaxf(b, 0.f));
#endif
}
__device__ __forceinline__ float dot2(u32 xp, u32 wp, float acc) {
#if __has_builtin(__builtin_amdgcn_fdot2)
  return __builtin_amdgcn_fdot2(__builtin_bit_cast(h2, xp), __builtin_bit_cast(h2, wp), acc, false);
#else
  h2 xv = __builtin_bit_cast(h2, xp), wv = __builtin_bit_cast(h2, wp);
  return acc + (float)xv[0] * (float)wv[0] + (float)xv[1] * (float)wv[1];
#endif
}
__device__ __forceinline__ u32 mergepair(u32 a, u32 b, int par) {
  return par ? ((a >> 16) | (b & 0xffff0000u))
             : ((a & 0x0000ffffu) | (b << 16));
}
__device__ __forceinline__ f32x4 mfma16(f16x8 a, f16x8 b, f32x4 c) {
  return __builtin_amdgcn_mfma_f32_16x16x32_f16(a, b, c, 0, 0, 0);
}
__device__ __forceinline__ f32x4 mfma16x16(f16x4 a, f16x4 b, f32x4 c) {
  return __builtin_amdgcn_mfma_f32_16x16x16f16(a, b, c, 0, 0, 0);
}

struct Frags {
  f16x8 a1[7][2];  // isft: d = 16*mt + (l&15), k=c = 32*kt + 8*(l>>4) + j (0 pad)
};

__device__ __forceinline__ f16x8 ldpair8(const char* base, int par) {
  const uint4 q0 = *(const uint4*)(base);
  const uint4 q1 = *(const uint4*)(base + 16);
  uint4 r;
  r.x = mergepair(q0.x, q0.y, par);
  r.y = mergepair(q0.z, q0.w, par);
  r.z = mergepair(q1.x, q1.y, par);
  r.w = mergepair(q1.z, q1.w, par);
  return __builtin_bit_cast(f16x8, r);
}

// ---------------- nonlin: GEMM1 (16x16x32) -> relu/pack -> GEMM2 (16x16x16,
// A = packed Y verbatim (m=r,k=d), B = sft frag from LDS (n=c,k=d) -> D[r,c]
template <bool TW>
__device__ void nonlin_tiles(const Frags& F, const uint4* p2,
                             const float* __restrict__ sft,
                             char* smem, int lane, int wid,
                             int T, int TA, int inArow, int inBrow,
                             int outArow, int outBrow) {
  const int i15 = lane & 15, g = lane >> 4;
  for (int t = wid; t < T; t += 4) {
    const int inrow = (t < TA) ? (inArow + t * 16) : (inBrow + (t - TA) * 16);
    const int outrow = (t < TA) ? (outArow + t * 16) : (outBrow + (t - TA) * 16);
    const int R = inrow + i15, par = R & 1;
    const char* ib = smem + (R >> 1) * PRB + g * 32;
    f16x8 b0 = ldpair8(ib, par);
    f16x8 b1 = ldpair8(ib + 128, par);
    f32x4 acc1[7];
#pragma unroll
    for (int mt = 0; mt < 7; ++mt) {
      f32x4 z = {0.f, 0.f, 0.f, 0.f};
      z = mfma16(F.a1[mt][0], b0, z);
      acc1[mt] = mfma16(F.a1[mt][1], b1, z);
    }
    // relu + pack: pk[kt] = Y[d = 16kt + 4g + j, r = i15] as 4 fp16 (2 dwords)
    u32 pk[7][2];
#pragma unroll
    for (int kt = 0; kt < 7; ++kt) {
      pk[kt][0] = pkrelu(acc1[kt][0], acc1[kt][1]);
      pk[kt][1] = pkrelu(acc1[kt][2], acc1[kt][3]);
    }
    // GEMM2: A = pk (m=r, k=d), B = sft frag (n=c, k=d) -> D[r, c]
    f32x4 acc2[3];
#pragma unroll
    for (int n = 0; n < 3; ++n) acc2[n] = (f32x4){0.f, 0.f, 0.f, 0.f};
#pragma unroll
    for (int q = 0; q < 4; ++q) {
      uint2 yw0; yw0.x = pk[2 * q][0]; yw0.y = pk[2 * q][1];
      const f16x4 yA = __builtin_bit_cast(f16x4, yw0);
      f16x4 yB = {};
      if (q < 3) {
        uint2 yw1; yw1.x = pk[2 * q + 1][0]; yw1.y = pk[2 * q + 1][1];
        yB = __builtin_bit_cast(f16x4, yw1);
      }
#pragma unroll
      for (int n = 0; n < 3; ++n) {
        f16x4 bA, bB;
        if constexpr (TW) {
          const uint4 aw = p2[(n * 4 + q) * 64 + lane];   // LDS-staged table
          uint2 lo; lo.x = aw.x; lo.y = aw.y;
          uint2 hi; hi.x = aw.z; hi.y = aw.w;
          bA = __builtin_bit_cast(f16x4, lo);
          bB = __builtin_bit_cast(f16x4, hi);
        } else {
          const int c0 = 16 * n + i15;
#pragma unroll
          for (int j = 0; j < 4; ++j) {
            const int dA = 32 * q + 4 * g + j;
            bA[j] = (half_t)((c0 < 45 && dA < 100) ? sft[c0 * 100 + dA] : 0.f);
            const int dB = 32 * q + 16 + 4 * g + j;
            bB[j] = (half_t)((c0 < 45 && dB < 100) ? sft[c0 * 100 + dB] : 0.f);
          }
        }
        acc2[n] = mfma16x16(yA, bA, acc2[n]);
        if (q < 3) acc2[n] = mfma16x16(yB, bB, acc2[n]);
      }
    }
    // write: lane owns col c = 16n + i15, rows outrow + 4g + {0..3}. Full dwords.
    char* ob = smem + ((outrow >> 1) + 2 * g) * PRB + i15 * 4;
#pragma unroll
    for (int n = 0; n < 3; ++n) {
      *(u32*)(ob + n * 64) = pk2(acc2[n][0], acc2[n][1]);
      *(u32*)(ob + PRB + n * 64) = pk2(acc2[n][2], acc2[n][3]);
    }
  }
}

// ---------------- sconv via MFMA (unchanged from r9/r11/r13)
template <int O, int I, int SPL, bool INPLACE>
__device__ void sconv_mfma(const uint4* __restrict__ afr, char* smem,
                           int lane, int wid, int inArow, int inBrow, int outrow) {
  constexpr int Mt = O / 16;
  constexpr int Kt = (I + 31) / 32;
  constexpr int CELLS = Mt * 6;
  constexpr int NCI = (CELLS + 3) / 4;
  constexpr bool CONCAT = (SPL < I);
  const int n15 = lane & 15, g = lane >> 4;

  f32x4 accs[INPLACE ? NCI : 1];

#pragma unroll
  for (int ci = 0; ci < NCI; ++ci) {
    const int cell = wid + 4 * ci;
    if (cell < CELLS) {
      const int mt = cell / 6, grp = cell - 6 * mt;
      const int l = (grp >= 1) + (grp >= 2) + (grp >= 3) + (grp >= 4);
      const int c0 = l * (2 * l - 1) + ((grp == 5) ? 16 : 0);
      const int c = c0 + n15;
      f32x4 acc = {0.f, 0.f, 0.f, 0.f};
#pragma unroll
      for (int kt = 0; kt < Kt; ++kt) {
        const f16x8 A = __builtin_bit_cast(f16x8, afr[((l * Mt + mt) * Kt + kt) * 64 + lane]);
        int basepair;
        if constexpr (CONCAT) {
          const int iA0 = 32 * kt + 8 * g;
          basepair = ((iA0 < SPL) ? (inArow + iA0) : (inBrow + iA0 - SPL)) >> 1;
        } else {
          basepair = (inArow >> 1) + 16 * kt + 4 * g;
        }
        const char* bp = smem + basepair * PRB + c * 4;
        uint4 b4;
        b4.x = *(const u32*)(bp);
        b4.y = *(const u32*)(bp + PRB);
        b4.z = *(const u32*)(bp + 2 * PRB);
        b4.w = *(const u32*)(bp + 3 * PRB);
        acc = mfma16(A, __builtin_bit_cast(f16x8, b4), acc);
      }
      if constexpr (INPLACE) {
        accs[ci] = acc;
      } else {
        const int sz = (grp == 4) ? 16 : (((grp == 0) || (grp == 5)) ? 1 : (4 * l + 1));
        if (n15 < sz) {
          char* wb = smem + ((outrow >> 1) + 8 * mt + 2 * g) * PRB + c * 4;
          *(u32*)(wb) = pk2(acc[0], acc[1]);
          *(u32*)(wb + PRB) = pk2(acc[2], acc[3]);
        }
      }
    }
  }
  if constexpr (INPLACE) {
    __syncthreads();
#pragma unroll
    for (int ci = 0; ci < NCI; ++ci) {
      const int cell = wid + 4 * ci;
      if (cell < CELLS) {
        const int mt = cell / 6, grp = cell - 6 * mt;
        const int l = (grp >= 1) + (grp >= 2) + (grp >= 3) + (grp >= 4);
        const int c0 = l * (2 * l - 1) + ((grp == 5) ? 16 : 0);
        const int sz = (grp == 4) ? 16 : (((grp == 0) || (grp == 5)) ? 1 : (4 * l + 1));
        const int c = c0 + n15;
        if (n15 < sz) {
          char* wb = smem + ((outrow >> 1) + 8 * mt + 2 * g) * PRB + c * 4;
          *(u32*)(wb) = pk2(accs[ci][0], accs[ci][1]);
          *(u32*)(wb + PRB) = pk2(accs[ci][2], accs[ci][3]);
        }
      }
    }
  }
  __syncthreads();
}

// ---------------- dot2 sconv (no-ws fallback only)
template <int O, int I, int SPL, int NSEG, int NIP, int SEG>
__device__ __forceinline__ void sconv_acc_p(const float* __restrict__ wf, int o, int ip,
                                            bool act, const char* smem, int inArow, int inBrow,
                                            float* acc) {
  constexpr int NC = 48 / NSEG;
  constexpr int NU4 = NC / 4;
  constexpr int C0 = SEG * NC;
#pragma unroll
  for (int k = 0; k < NC; ++k) acc[k] = 0.f;
  if (!act) return;
#pragma unroll 2
  for (int p = ip; p < I / 2; p += NIP) {
    const int rA = 2 * p;
    const char* rb = smem +
        (((rA < SPL) ? ((inArow >> 1) + p) : ((inBrow >> 1) + p - SPL / 2)) * PRB) + C0 * 4;
    u32 wv[5];
#pragma unroll
    for (int l = 0; l < 5; ++l)
      wv[l] = pk2rne(wf[(o * I + rA) * 5 + l], wf[(o * I + rA + 1) * 5 + l]);
#pragma unroll
    for (int k = 0; k < NU4; ++k) {
      const uint4 q = *(const uint4*)(rb + k * 16);
      const u32 qq[4] = {q.x, q.y, q.z, q.w};
#pragma unroll
      for (int j = 0; j < 4; ++j) {
        const int c = C0 + k * 4 + j;
        acc[k * 4 + j] = dot2(qq[j], wv[l_of(c)], acc[k * 4 + j]);
      }
    }
  }
}

template <int NSEG, int SEG>
__device__ __forceinline__ void sconv_write_p(char* smem, int outrow, int o, const float* acc) {
  constexpr int NC = 48 / NSEG;
  constexpr int C0 = SEG * NC;
  const int R = outrow + o;
  char* wb = smem + (R >> 1) * PRB + (R & 1) * 2 + C0 * 4;
#pragma unroll
  for (int k = 0; k < NC; ++k) {
    const int c = C0 + k;
    *(half_t*)(wb + k * 4) = (half_t)(acc[k] * lfac_of(l_of(c)));
  }
}

template <int O, int I, int SPL, int NSEG, int NIP>
__device__ void sconv_layer(const float* __restrict__ wf, char* smem, int tid,
                            int inArow, int inBrow, int outrow) {
  constexpr int NC = 48 / NSEG;
  const int ip = (NIP == 1) ? 0 : (tid % NIP);
  const int seg = (tid / NIP) % NSEG;
  const int o = tid / (NIP * NSEG);
  const bool act = (o < O);
  float acc[NC];
  if (seg == 0)
    sconv_acc_p<O, I, SPL, NSEG, NIP, 0>(wf, o, ip, act, smem, inArow, inBrow, acc);
  else if (seg == 1)
    sconv_acc_p<O, I, SPL, NSEG, NIP, 1>(wf, o, ip, act, smem, inArow, inBrow, acc);
  else if constexpr (NSEG > 2) {
    sconv_acc_p<O, I, SPL, NSEG, NIP, 2>(wf, o, ip, act, smem, inArow, inBrow, acc);
  }
  if constexpr (NIP >= 2) {
#pragma unroll
    for (int k = 0; k < NC; ++k) acc[k] += __shfl_xor(acc[k], 1);
  }
  if constexpr (NIP >= 4) {
#pragma unroll
    for (int k = 0; k < NC; ++k) acc[k] += __shfl_xor(acc[k], 2);
  }
  __syncthreads();
  if (act && ip == 0) {
    if (seg == 0) sconv_write_p<NSEG, 0>(smem, outrow, o, acc);
    else if (seg == 1) sconv_write_p<NSEG, 1>(smem, outrow, o, acc);
    else if constexpr (NSEG > 2) { sconv_write_p<NSEG, 2>(smem, outrow, o, acc); }
  }
  __syncthreads();
}

// ---------------- prep: bake nonlin frags + sconv A-frags into ws
__global__ void scnn_prep(const float* __restrict__ sft, const float* __restrict__ isft,
                          const float* __restrict__ w1, const float* __restrict__ w2,
                          const float* __restrict__ w3, const float* __restrict__ w4,
                          const float* __restrict__ w5, const float* __restrict__ w6,
                          const float* __restrict__ w7, const float* __restrict__ w8,
                          const float* __restrict__ w9, u32* __restrict__ wsbuf) {
  const int gid = blockIdx.x * 256 + threadIdx.x;
  if (gid < 3584) {  // A1 frags (isft), 16x16x32 convention
    const int f = gid >> 8, r = gid & 255, ln = r >> 2, wd = r & 3;
    const int mt = f >> 1, kt = f & 1;
    const int d = 16 * mt + (ln & 15);
    const int c = 32 * kt + 8 * (ln >> 4) + 2 * wd;
    const float v0 = (d < 100 && c < 45) ? isft[d * 45 + c] : 0.f;
    const float v1 = (d < 100 && c + 1 < 45) ? isft[d * 45 + c + 1] : 0.f;
    wsbuf[gid] = pk2rne(v0, v1);
  } else if (gid < WS_FRAG_U32) {  // sft frag-pairs, 16x16x16 convention
    const int e = gid - 3584;
    const int f = e >> 8, r = e & 255, ln = r >> 2, wd = r & 3;
    const int m = f >> 2, q = f & 3;
    const int kt = 2 * q + (wd >> 1);
    const int c = 16 * m + (ln & 15);
    const int d = 16 * kt + 4 * (ln >> 4) + 2 * (wd & 1);
    const float v0 = (kt < 7 && c < 45 && d < 100) ? sft[c * 100 + d] : 0.f;
    const float v1 = (kt < 7 && c < 45 && d + 1 < 100) ? sft[c * 100 + d + 1] : 0.f;
    wsbuf[gid] = pk2rne(v0, v1);
  } else if (gid < WS_FRAG_U32 + WS_AFRAG_U32) {  // sconv A-frags, lfac folded
    const int e = gid - WS_FRAG_U32;
    const int frag = e >> 8, r = e & 255, ln = r >> 2, wd = r & 3;
    const float* src; int O, I, Mt, Kt, off;
    if (frag < 5)        { src = w1; O = 16;  I = 4;   Mt = 1; Kt = 1; off = 0;   }
    else if (frag < 15)  { src = w2; O = 32;  I = 16;  Mt = 2; Kt = 1; off = 5;   }
    else if (frag < 35)  { src = w3; O = 64;  I = 32;  Mt = 4; Kt = 1; off = 15;  }
    else if (frag < 115) { src = w4; O = 128; I = 64;  Mt = 8; Kt = 2; off = 35;  }
    else if (frag < 195) { src = w5; O = 64;  I = 128; Mt = 4; Kt = 4; off = 115; }
    else if (frag < 235) { src = w6; O = 32;  I = 128; Mt = 2; Kt = 4; off = 195; }
    else if (frag < 245) { src = w7; O = 16;  I = 64;  Mt = 1; Kt = 2; off = 235; }
    else                 { src = w8; O = 16;  I = 32;  Mt = 1; Kt = 1; off = 245; }
    const int fl = frag - off;
    const int l = fl / (Mt * Kt), rem = fl % (Mt * Kt);
    const int mt = rem / Kt, kt = rem % Kt;
    const int o = 16 * mt + (ln & 15);
    const int i0 = 32 * kt + 8 * (ln >> 4) + 2 * wd;
    const float lf = lfac_of(l);
    const float v0 = (i0 < I) ? src[(o * I + i0) * 5 + l] * lf : 0.f;
    const float v1 = (i0 + 1 < I) ? src[(o * I + i0 + 1) * 5 + l] * lf : 0.f;
    wsbuf[gid] = pk2rne(v0, v1);
  }
  (void)w9;
}

// ---------------- main fused kernel
template <bool TW>
__global__ __launch_bounds__(256, 3) void scnn_mfma(
    const float* __restrict__ x, const float* __restrict__ sft, const float* __restrict__ isft,
    const float* __restrict__ w1, const float* __restrict__ w2, const float* __restrict__ w3,
    const float* __restrict__ w4, const float* __restrict__ w5, const float* __restrict__ w6,
    const float* __restrict__ w7, const float* __restrict__ w8, const float* __restrict__ w9,
    const u32* __restrict__ wsbuf, float* __restrict__ out) {
  constexpr int SMB = ACTB + (TW ? P2N * 16 : 0);
  __shared__ __align__(16) char smem[SMB];
  const int tid = threadIdx.x, lane = tid & 63, wid = tid >> 6, b = blockIdx.x;
  const uint4* afrB = TW ? ((const uint4*)wsbuf) + (WS_FRAG_U32 / 4) : nullptr;
  uint4* p2s = TW ? (uint4*)(smem + ACTB) : nullptr;

  Frags F;
  if constexpr (TW) {
    const uint4* p1 = (const uint4*)wsbuf;
#pragma unroll
    for (int f = 0; f < 14; ++f)
      F.a1[f / 2][f % 2] = __builtin_bit_cast(f16x8, p1[f * 64 + lane]);
    // stage full p2 table (768 uint4 = 12288B) into LDS
    const uint4* p2g = p1 + 14 * 64;
    for (int i = tid; i < P2N; i += 256) p2s[i] = p2g[i];
  } else {
    const int i15 = lane & 15, g = lane >> 4;
#pragma unroll
    for (int mt = 0; mt < 7; ++mt)
#pragma unroll
      for (int kt = 0; kt < 2; ++kt) {
        const int d = 16 * mt + i15;
        f16x8 v;
#pragma unroll
        for (int j = 0; j < 8; ++j) {
          const int c = 32 * kt + 8 * g + j;
          v[j] = (half_t)((d < 100 && c < 45) ? isft[d * 45 + c] : 0.f);
        }
        F.a1[mt][kt] = v;
      }
  }

  // zero the activation buffer (K-padded MFMA B-reads must see finite zeros)
  for (int idx = tid; idx < ACTB / 4; idx += 256)
    ((u32*)smem)[idx] = 0u;
  __syncthreads();
  // stage x [4,45] -> rows 0..3 (paired layout)
  if (tid < 192) {
    const int r = tid / 48, c = tid % 48;
    const float v = (c < 45) ? x[b * 180 + r * 45 + c] : 0.f;
    *(half_t*)(smem + (r >> 1) * PRB + c * 4 + (r & 1) * 2) = (half_t)v;
  }
  __syncthreads();

  if constexpr (TW) {
    sconv_mfma<16, 4, 4, true>(afrB + 0 * 64, smem, lane, wid, 0, 0, 0);
    nonlin_tiles<TW>(F, p2s, sft, smem, lane, wid, 1, 1, 0, 0, E1R, E1R);
    __syncthreads();
    sconv_mfma<32, 16, 16, false>(afrB + 5 * 64, smem, lane, wid, E1R, E1R, 0);
    nonlin_tiles<TW>(F, p2s, sft, smem, lane, wid, 2, 2, 0, 0, E2R, E2R);
    __syncthreads();
    sconv_mfma<64, 32, 32, false>(afrB + 15 * 64, smem, lane, wid, E2R, E2R, 0);
    nonlin_tiles<TW>(F, p2s, sft, smem, lane, wid, 4, 4, 0, 0, E3R, E3R);
    __syncthreads();
    sconv_mfma<128, 64, 64, false>(afrB + 35 * 64, smem, lane, wid, E3R, E3R, 0);
    nonlin_tiles<TW>(F, p2s, sft, smem, lane, wid, 8, 8, 0, 0, 0, 0);
    __syncthreads();
    sconv_mfma<64, 128, 128, true>(afrB + 115 * 64, smem, lane, wid, 0, 0, 0);
    nonlin_tiles<TW>(F, p2s, sft, smem, lane, wid, 8, 4, 0, E3R, 0, E3R);
    __syncthreads();
    sconv_mfma<32, 128, 64, true>(afrB + 195 * 64, smem, lane, wid, 0, E3R, 0);
    nonlin_tiles<TW>(F, p2s, sft, smem, lane, wid, 4, 2, 0, E2R, 0, E2R);
    __syncthreads();
    sconv_mfma<16, 64, 32, true>(afrB + 235 * 64, smem, lane, wid, 0, E2R, 0);
    nonlin_tiles<TW>(F, p2s, sft, smem, lane, wid, 2, 1, 0, E1R, 0, E1R);
    __syncthreads();
    sconv_mfma<16, 32, 16, true>(afrB + 245 * 64, smem, lane, wid, 0, E1R, 0);
    nonlin_tiles<TW>(F, p2s, sft, smem, lane, wid, 1, 1, 0, 0, 0, 0);
    __syncthreads();
  } else {
    sconv_layer<16, 4, 4, 3, 4>(w1, smem, tid, 0, 0, 0);
    nonlin_tiles<TW>(F, nullptr, sft, smem, lane, wid, 1, 1, 0, 0, E1R, E1R);
    __syncthreads();
    sconv_layer<32, 16, 16, 2, 4>(w2, smem, tid, E1R, E1R, 0);
    nonlin_tiles<TW>(F, nullptr, sft, smem, lane, wid, 2, 2, 0, 0, E2R, E2R);
    __syncthreads();
    sconv_layer<64, 32, 32, 2, 2>(w3, smem, tid, E2R, E2R, 0);
    nonlin_tiles<TW>(F, nullptr, sft, smem, lane, wid, 4, 4, 0, 0, E3R, E3R);
    __syncthreads();
    sconv_layer<128, 64, 64, 2, 1>(w4, smem, tid, E3R, E3R, 0);
    nonlin_tiles<TW>(F, nullptr, sft, smem, lane, wid, 8, 8, 0, 0, 0, 0);
    __syncthreads();
    sconv_layer<64, 128, 128, 2, 2>(w5, smem, tid, 0, 0, 0);
    nonlin_tiles<TW>(F, nullptr, sft, smem, lane, wid, 8, 4, 0, E3R, 0, E3R);
    __syncthreads();
    sconv_layer<32, 128, 64, 2, 4>(w6, smem, tid, 0, E3R, 0);
    nonlin_tiles<TW>(F, nullptr, sft, smem, lane, wid, 4, 2, 0, E2R, 0, E2R);
    __syncthreads();
    sconv_layer<16, 64, 32, 3, 4>(w7, smem, tid, 0, E2R, 0);
    nonlin_tiles<TW>(F, nullptr, sft, smem, lane, wid, 2, 1, 0, E1R, 0, E1R);
    __syncthreads();
    sconv_layer<16, 32, 16, 3, 4>(w8, smem, tid, 0, E1R, 0);
    nonlin_tiles<TW>(F, nullptr, sft, smem, lane, wid, 1, 1, 0, 0, 0, 0);
    __syncthreads();
  }

  // final sconv: O=1, I=16 (d4 rows 0..15) -> out[b,c] fp32
  if (tid < 45) {
    const int c = tid, l = l_of(c);
    float acc = 0.f;
#pragma unroll
    for (int i = 0; i < 16; ++i)
      acc += w9[i * 5 + l] *
             (float)(*(const half_t*)(smem + (i >> 1) * PRB + c * 4 + (i & 1) * 2));
    out[b * 45 + c] = acc * lfac_of(l);
  }
}

extern "C" void kernel_launch(void* const* d_in, const int* in_sizes, int n_in,
                              void* d_out, int out_size, void* d_ws, size_t ws_size,
                              hipStream_t stream) {
  (void)n_in; (void)out_size;
  const float* x    = (const float*)d_in[0];
  const float* sft  = (const float*)d_in[1];
  const float* isft = (const float*)d_in[2];
  const float* w1 = (const float*)d_in[3];
  const float* w2 = (const float*)d_in[4];
  const float* w3 = (const float*)d_in[5];
  const float* w4 = (const float*)d_in[6];
  const float* w5 = (const float*)d_in[7];
  const float* w6 = (const float*)d_in[8];
  const float* w7 = (const float*)d_in[9];
  const float* w8 = (const float*)d_in[10];
  const float* w9 = (const float*)d_in[11];
  float* out = (float*)d_out;

  const int batch = in_sizes[0] / 180;  // 16384

  if (ws_size >= (size_t)WS_NEEDED) {
    u32* wsbuf = (u32*)d_ws;
    const int prepN = WS_FRAG_U32 + WS_AFRAG_U32;
    hipLaunchKernelGGL(scnn_prep, dim3((prepN + 255) / 256), dim3(256), 0, stream,
                       sft, isft, w1, w2, w3, w4, w5, w6, w7, w8, w9, wsbuf);
    hipLaunchKernelGGL((scnn_mfma<true>), dim3(batch), dim3(256), 0, stream,
                       x, sft, isft, w1, w2, w3, w4, w5, w6, w7, w8, w9, wsbuf, out);
  } else {
    hipLaunchKernelGGL((scnn_mfma<false>), dim3(batch), dim3(256), 0, stream,
                       x, sft, isft, w1, w2, w3, w4, w5, w6, w7, w8, w9,
                       (const u32*)nullptr, out);
  }
}

// Round 19
// 514.511 us; speedup vs baseline: 1.1689x; 1.0013x over previous
//
#include <hip/hip_runtime.h>
#include <math.h>

// SCNN fused, round 19: r16/r18 base (515us) + barrier reduction: layers
// w1/w6/w7/w8 write to a 32-row LDS scratch (rows 240..271) instead of
// in-place -> single-barrier sconv (removes 4 of ~22 block barriers).
// w5 (64-row out, doesn't fit budget) stays INPLACE. Inner bodies untouched.
// LDS 45056 -> ~49.3KB; 3 blocks/CU preserved (148KB < 160KB).

typedef _Float16 half_t;
typedef _Float16 f16x8 __attribute__((ext_vector_type(8)));
typedef _Float16 f16x4 __attribute__((ext_vector_type(4)));
typedef __fp16 h2 __attribute__((ext_vector_type(2)));
typedef float f32x4 __attribute__((ext_vector_type(4)));
typedef unsigned int u32;

#define PRB 272    // bytes per pair-row: 64 c * 4B + 16 slack; conflict-free rows
#define NPAIRS 136 // 240 activation rows + 32 scratch rows (pairs 120..135)
#define ACTB (NPAIRS * PRB)  // 36992 B
#define P2N 768    // p2 table: 12 frag-pairs * 64 lanes (uint4)
#define E1R 128
#define E2R 144
#define E3R 176
#define SCR 240    // scratch row base (rows 240..271)

// ws layout (u32): [0,3584) A1 frags, [3584,6656) sft frag-pairs (16x16x16),
// [6656, +64000) sconv A-frags
#define WS_FRAG_U32 6656
#define WS_AFRAG_U32 64000
#define WS_NEEDED ((WS_FRAG_U32 + WS_AFRAG_U32) * 4)

__device__ __host__ __forceinline__ constexpr int l_of(int c) {
  return (c >= 1) + (c >= 6) + (c >= 15) + (c >= 28);
}
__device__ __forceinline__ float lfac_of(int l) {
  return sqrtf(3.14159265358979323846f / (float)(4 * l + 1));
}
__device__ __forceinline__ u32 pk2(float a, float b) {
  auto v = __builtin_amdgcn_cvt_pkrtz(a, b);
  return __builtin_bit_cast(u32, v);
}
__device__ __forceinline__ u32 pk2rne(float a, float b) {
  unsigned short lo = __builtin_bit_cast(unsigned short, (half_t)a);
  unsigned short hi = __builtin_bit_cast(unsigned short, (half_t)b);
  return (u32)lo | ((u32)hi << 16);
}
__device__ __forceinline__ u32 pkrelu(float a, float b) {
#if defined(__has_builtin) && __has_builtin(__builtin_elementwise_max)
  u32 v = pk2(a, b);
  h2 hv = __builtin_bit_cast(h2, v);
  h2 z = {};
  hv = __builtin_elementwise_max(hv, z);
  return __builtin_bit_cast(u32, hv);
#else
  return pk2(fmaxf(a, 0.f), fmaxf(b, 0.f));
#endif
}
__device__ __forceinline__ float dot2(u32 xp, u32 wp, float acc) {
#if __has_builtin(__builtin_amdgcn_fdot2)
  return __builtin_amdgcn_fdot2(__builtin_bit_cast(h2, xp), __builtin_bit_cast(h2, wp), acc, false);
#else
  h2 xv = __builtin_bit_cast(h2, xp), wv = __builtin_bit_cast(h2, wp);
  return acc + (float)xv[0] * (float)wv[0] + (float)xv[1] * (float)wv[1];
#endif
}
__device__ __forceinline__ u32 mergepair(u32 a, u32 b, int par) {
  return par ? ((a >> 16) | (b & 0xffff0000u))
             : ((a & 0x0000ffffu) | (b << 16));
}
__device__ __forceinline__ f32x4 mfma16(f16x8 a, f16x8 b, f32x4 c) {
  return __builtin_amdgcn_mfma_f32_16x16x32_f16(a, b, c, 0, 0, 0);
}
__device__ __forceinline__ f32x4 mfma16x16(f16x4 a, f16x4 b, f32x4 c) {
  return __builtin_amdgcn_mfma_f32_16x16x16f16(a, b, c, 0, 0, 0);
}

struct Frags {
  f16x8 a1[7][2];  // isft: d = 16*mt + (l&15), k=c = 32*kt + 8*(l>>4) + j (0 pad)
};

__device__ __forceinline__ f16x8 ldpair8(const char* base, int par) {
  const uint4 q0 = *(const uint4*)(base);
  const uint4 q1 = *(const uint4*)(base + 16);
  uint4 r;
  r.x = mergepair(q0.x, q0.y, par);
  r.y = mergepair(q0.z, q0.w, par);
  r.z = mergepair(q1.x, q1.y, par);
  r.w = mergepair(q1.z, q1.w, par);
  return __builtin_bit_cast(f16x8, r);
}

// ---------------- nonlin (body identical to r16/r18)
template <bool TW>
__device__ void nonlin_tiles(const Frags& F, const uint4* p2,
                             const float* __restrict__ sft,
                             char* smem, int lane, int wid,
                             int T, int TA, int inArow, int inBrow,
                             int outArow, int outBrow) {
  const int i15 = lane & 15, g = lane >> 4;
  for (int t = wid; t < T; t += 4) {
    const int inrow = (t < TA) ? (inArow + t * 16) : (inBrow + (t - TA) * 16);
    const int outrow = (t < TA) ? (outArow + t * 16) : (outBrow + (t - TA) * 16);
    const int R = inrow + i15, par = R & 1;
    const char* ib = smem + (R >> 1) * PRB + g * 32;
    f16x8 b0 = ldpair8(ib, par);
    f16x8 b1 = ldpair8(ib + 128, par);
    f32x4 acc1[7];
#pragma unroll
    for (int mt = 0; mt < 7; ++mt) {
      f32x4 z = {0.f, 0.f, 0.f, 0.f};
      z = mfma16(F.a1[mt][0], b0, z);
      acc1[mt] = mfma16(F.a1[mt][1], b1, z);
    }
    u32 pk[7][2];
#pragma unroll
    for (int kt = 0; kt < 7; ++kt) {
      pk[kt][0] = pkrelu(acc1[kt][0], acc1[kt][1]);
      pk[kt][1] = pkrelu(acc1[kt][2], acc1[kt][3]);
    }
    f32x4 acc2[3];
#pragma unroll
    for (int n = 0; n < 3; ++n) acc2[n] = (f32x4){0.f, 0.f, 0.f, 0.f};
#pragma unroll
    for (int q = 0; q < 4; ++q) {
      uint2 yw0; yw0.x = pk[2 * q][0]; yw0.y = pk[2 * q][1];
      const f16x4 yA = __builtin_bit_cast(f16x4, yw0);
      f16x4 yB = {};
      if (q < 3) {
        uint2 yw1; yw1.x = pk[2 * q + 1][0]; yw1.y = pk[2 * q + 1][1];
        yB = __builtin_bit_cast(f16x4, yw1);
      }
#pragma unroll
      for (int n = 0; n < 3; ++n) {
        f16x4 bA, bB;
        if constexpr (TW) {
          const uint4 aw = p2[(n * 4 + q) * 64 + lane];   // LDS-staged table
          uint2 lo; lo.x = aw.x; lo.y = aw.y;
          uint2 hi; hi.x = aw.z; hi.y = aw.w;
          bA = __builtin_bit_cast(f16x4, lo);
          bB = __builtin_bit_cast(f16x4, hi);
        } else {
          const int c0 = 16 * n + i15;
#pragma unroll
          for (int j = 0; j < 4; ++j) {
            const int dA = 32 * q + 4 * g + j;
            bA[j] = (half_t)((c0 < 45 && dA < 100) ? sft[c0 * 100 + dA] : 0.f);
            const int dB = 32 * q + 16 + 4 * g + j;
            bB[j] = (half_t)((c0 < 45 && dB < 100) ? sft[c0 * 100 + dB] : 0.f);
          }
        }
        acc2[n] = mfma16x16(yA, bA, acc2[n]);
        if (q < 3) acc2[n] = mfma16x16(yB, bB, acc2[n]);
      }
    }
    char* ob = smem + ((outrow >> 1) + 2 * g) * PRB + i15 * 4;
#pragma unroll
    for (int n = 0; n < 3; ++n) {
      *(u32*)(ob + n * 64) = pk2(acc2[n][0], acc2[n][1]);
      *(u32*)(ob + PRB + n * 64) = pk2(acc2[n][2], acc2[n][3]);
    }
  }
}

// ---------------- sconv via MFMA (body identical; INPLACE only for w5 now)
template <int O, int I, int SPL, bool INPLACE>
__device__ void sconv_mfma(const uint4* __restrict__ afr, char* smem,
                           int lane, int wid, int inArow, int inBrow, int outrow) {
  constexpr int Mt = O / 16;
  constexpr int Kt = (I + 31) / 32;
  constexpr int CELLS = Mt * 6;
  constexpr int NCI = (CELLS + 3) / 4;
  constexpr bool CONCAT = (SPL < I);
  const int n15 = lane & 15, g = lane >> 4;

  f32x4 accs[INPLACE ? NCI : 1];

#pragma unroll
  for (int ci = 0; ci < NCI; ++ci) {
    const int cell = wid + 4 * ci;
    if (cell < CELLS) {
      const int mt = cell / 6, grp = cell - 6 * mt;
      const int l = (grp >= 1) + (grp >= 2) + (grp >= 3) + (grp >= 4);
      const int c0 = l * (2 * l - 1) + ((grp == 5) ? 16 : 0);
      const int c = c0 + n15;
      f32x4 acc = {0.f, 0.f, 0.f, 0.f};
#pragma unroll
      for (int kt = 0; kt < Kt; ++kt) {
        const f16x8 A = __builtin_bit_cast(f16x8, afr[((l * Mt + mt) * Kt + kt) * 64 + lane]);
        int basepair;
        if constexpr (CONCAT) {
          const int iA0 = 32 * kt + 8 * g;
          basepair = ((iA0 < SPL) ? (inArow + iA0) : (inBrow + iA0 - SPL)) >> 1;
        } else {
          basepair = (inArow >> 1) + 16 * kt + 4 * g;
        }
        const char* bp = smem + basepair * PRB + c * 4;
        uint4 b4;
        b4.x = *(const u32*)(bp);
        b4.y = *(const u32*)(bp + PRB);
        b4.z = *(const u32*)(bp + 2 * PRB);
        b4.w = *(const u32*)(bp + 3 * PRB);
        acc = mfma16(A, __builtin_bit_cast(f16x8, b4), acc);
      }
      if constexpr (INPLACE) {
        accs[ci] = acc;
      } else {
        const int sz = (grp == 4) ? 16 : (((grp == 0) || (grp == 5)) ? 1 : (4 * l + 1));
        if (n15 < sz) {
          char* wb = smem + ((outrow >> 1) + 8 * mt + 2 * g) * PRB + c * 4;
          *(u32*)(wb) = pk2(acc[0], acc[1]);
          *(u32*)(wb + PRB) = pk2(acc[2], acc[3]);
        }
      }
    }
  }
  if constexpr (INPLACE) {
    __syncthreads();
#pragma unroll
    for (int ci = 0; ci < NCI; ++ci) {
      const int cell = wid + 4 * ci;
      if (cell < CELLS) {
        const int mt = cell / 6, grp = cell - 6 * mt;
        const int l = (grp >= 1) + (grp >= 2) + (grp >= 3) + (grp >= 4);
        const int c0 = l * (2 * l - 1) + ((grp == 5) ? 16 : 0);
        const int sz = (grp == 4) ? 16 : (((grp == 0) || (grp == 5)) ? 1 : (4 * l + 1));
        const int c = c0 + n15;
        if (n15 < sz) {
          char* wb = smem + ((outrow >> 1) + 8 * mt + 2 * g) * PRB + c * 4;
          *(u32*)(wb) = pk2(accs[ci][0], accs[ci][1]);
          *(u32*)(wb + PRB) = pk2(accs[ci][2], accs[ci][3]);
        }
      }
    }
  }
  __syncthreads();
}

// ---------------- dot2 sconv (no-ws fallback only)
template <int O, int I, int SPL, int NSEG, int NIP, int SEG>
__device__ __forceinline__ void sconv_acc_p(const float* __restrict__ wf, int o, int ip,
                                            bool act, const char* smem, int inArow, int inBrow,
                                            float* acc) {
  constexpr int NC = 48 / NSEG;
  constexpr int NU4 = NC / 4;
  constexpr int C0 = SEG * NC;
#pragma unroll
  for (int k = 0; k < NC; ++k) acc[k] = 0.f;
  if (!act) return;
#pragma unroll 2
  for (int p = ip; p < I / 2; p += NIP) {
    const int rA = 2 * p;
    const char* rb = smem +
        (((rA < SPL) ? ((inArow >> 1) + p) : ((inBrow >> 1) + p - SPL / 2)) * PRB) + C0 * 4;
    u32 wv[5];
#pragma unroll
    for (int l = 0; l < 5; ++l)
      wv[l] = pk2rne(wf[(o * I + rA) * 5 + l], wf[(o * I + rA + 1) * 5 + l]);
#pragma unroll
    for (int k = 0; k < NU4; ++k) {
      const uint4 q = *(const uint4*)(rb + k * 16);
      const u32 qq[4] = {q.x, q.y, q.z, q.w};
#pragma unroll
      for (int j = 0; j < 4; ++j) {
        const int c = C0 + k * 4 + j;
        acc[k * 4 + j] = dot2(qq[j], wv[l_of(c)], acc[k * 4 + j]);
      }
    }
  }
}

template <int NSEG, int SEG>
__device__ __forceinline__ void sconv_write_p(char* smem, int outrow, int o, const float* acc) {
  constexpr int NC = 48 / NSEG;
  constexpr int C0 = SEG * NC;
  const int R = outrow + o;
  char* wb = smem + (R >> 1) * PRB + (R & 1) * 2 + C0 * 4;
#pragma unroll
  for (int k = 0; k < NC; ++k) {
    const int c = C0 + k;
    *(half_t*)(wb + k * 4) = (half_t)(acc[k] * lfac_of(l_of(c)));
  }
}

template <int O, int I, int SPL, int NSEG, int NIP>
__device__ void sconv_layer(const float* __restrict__ wf, char* smem, int tid,
                            int inArow, int inBrow, int outrow) {
  constexpr int NC = 48 / NSEG;
  const int ip = (NIP == 1) ? 0 : (tid % NIP);
  const int seg = (tid / NIP) % NSEG;
  const int o = tid / (NIP * NSEG);
  const bool act = (o < O);
  float acc[NC];
  if (seg == 0)
    sconv_acc_p<O, I, SPL, NSEG, NIP, 0>(wf, o, ip, act, smem, inArow, inBrow, acc);
  else if (seg == 1)
    sconv_acc_p<O, I, SPL, NSEG, NIP, 1>(wf, o, ip, act, smem, inArow, inBrow, acc);
  else if constexpr (NSEG > 2) {
    sconv_acc_p<O, I, SPL, NSEG, NIP, 2>(wf, o, ip, act, smem, inArow, inBrow, acc);
  }
  if constexpr (NIP >= 2) {
#pragma unroll
    for (int k = 0; k < NC; ++k) acc[k] += __shfl_xor(acc[k], 1);
  }
  if constexpr (NIP >= 4) {
#pragma unroll
    for (int k = 0; k < NC; ++k) acc[k] += __shfl_xor(acc[k], 2);
  }
  __syncthreads();
  if (act && ip == 0) {
    if (seg == 0) sconv_write_p<NSEG, 0>(smem, outrow, o, acc);
    else if (seg == 1) sconv_write_p<NSEG, 1>(smem, outrow, o, acc);
    else if constexpr (NSEG > 2) { sconv_write_p<NSEG, 2>(smem, outrow, o, acc); }
  }
  __syncthreads();
}

// ---------------- prep: bake nonlin frags + sconv A-frags into ws
__global__ void scnn_prep(const float* __restrict__ sft, const float* __restrict__ isft,
                          const float* __restrict__ w1, const float* __restrict__ w2,
                          const float* __restrict__ w3, const float* __restrict__ w4,
                          const float* __restrict__ w5, const float* __restrict__ w6,
                          const float* __restrict__ w7, const float* __restrict__ w8,
                          const float* __restrict__ w9, u32* __restrict__ wsbuf) {
  const int gid = blockIdx.x * 256 + threadIdx.x;
  if (gid < 3584) {  // A1 frags (isft), 16x16x32 convention
    const int f = gid >> 8, r = gid & 255, ln = r >> 2, wd = r & 3;
    const int mt = f >> 1, kt = f & 1;
    const int d = 16 * mt + (ln & 15);
    const int c = 32 * kt + 8 * (ln >> 4) + 2 * wd;
    const float v0 = (d < 100 && c < 45) ? isft[d * 45 + c] : 0.f;
    const float v1 = (d < 100 && c + 1 < 45) ? isft[d * 45 + c + 1] : 0.f;
    wsbuf[gid] = pk2rne(v0, v1);
  } else if (gid < WS_FRAG_U32) {  // sft frag-pairs, 16x16x16 convention
    const int e = gid - 3584;
    const int f = e >> 8, r = e & 255, ln = r >> 2, wd = r & 3;
    const int m = f >> 2, q = f & 3;
    const int kt = 2 * q + (wd >> 1);
    const int c = 16 * m + (ln & 15);
    const int d = 16 * kt + 4 * (ln >> 4) + 2 * (wd & 1);
    const float v0 = (kt < 7 && c < 45 && d < 100) ? sft[c * 100 + d] : 0.f;
    const float v1 = (kt < 7 && c < 45 && d + 1 < 100) ? sft[c * 100 + d + 1] : 0.f;
    wsbuf[gid] = pk2rne(v0, v1);
  } else if (gid < WS_FRAG_U32 + WS_AFRAG_U32) {  // sconv A-frags, lfac folded
    const int e = gid - WS_FRAG_U32;
    const int frag = e >> 8, r = e & 255, ln = r >> 2, wd = r & 3;
    const float* src; int O, I, Mt, Kt, off;
    if (frag < 5)        { src = w1; O = 16;  I = 4;   Mt = 1; Kt = 1; off = 0;   }
    else if (frag < 15)  { src = w2; O = 32;  I = 16;  Mt = 2; Kt = 1; off = 5;   }
    else if (frag < 35)  { src = w3; O = 64;  I = 32;  Mt = 4; Kt = 1; off = 15;  }
    else if (frag < 115) { src = w4; O = 128; I = 64;  Mt = 8; Kt = 2; off = 35;  }
    else if (frag < 195) { src = w5; O = 64;  I = 128; Mt = 4; Kt = 4; off = 115; }
    else if (frag < 235) { src = w6; O = 32;  I = 128; Mt = 2; Kt = 4; off = 195; }
    else if (frag < 245) { src = w7; O = 16;  I = 64;  Mt = 1; Kt = 2; off = 235; }
    else                 { src = w8; O = 16;  I = 32;  Mt = 1; Kt = 1; off = 245; }
    const int fl = frag - off;
    const int l = fl / (Mt * Kt), rem = fl % (Mt * Kt);
    const int mt = rem / Kt, kt = rem % Kt;
    const int o = 16 * mt + (ln & 15);
    const int i0 = 32 * kt + 8 * (ln >> 4) + 2 * wd;
    const float lf = lfac_of(l);
    const float v0 = (i0 < I) ? src[(o * I + i0) * 5 + l] * lf : 0.f;
    const float v1 = (i0 + 1 < I) ? src[(o * I + i0 + 1) * 5 + l] * lf : 0.f;
    wsbuf[gid] = pk2rne(v0, v1);
  }
  (void)w9;
}

// ---------------- main fused kernel
template <bool TW>
__global__ __launch_bounds__(256, 3) void scnn_mfma(
    const float* __restrict__ x, const float* __restrict__ sft, const float* __restrict__ isft,
    const float* __restrict__ w1, const float* __restrict__ w2, const float* __restrict__ w3,
    const float* __restrict__ w4, const float* __restrict__ w5, const float* __restrict__ w6,
    const float* __restrict__ w7, const float* __restrict__ w8, const float* __restrict__ w9,
    const u32* __restrict__ wsbuf, float* __restrict__ out) {
  constexpr int SMB = ACTB + (TW ? P2N * 16 : 0);
  __shared__ __align__(16) char smem[SMB];
  const int tid = threadIdx.x, lane = tid & 63, wid = tid >> 6, b = blockIdx.x;
  const uint4* afrB = TW ? ((const uint4*)wsbuf) + (WS_FRAG_U32 / 4) : nullptr;
  uint4* p2s = TW ? (uint4*)(smem + ACTB) : nullptr;

  Frags F;
  if constexpr (TW) {
    const uint4* p1 = (const uint4*)wsbuf;
#pragma unroll
    for (int f = 0; f < 14; ++f)
      F.a1[f / 2][f % 2] = __builtin_bit_cast(f16x8, p1[f * 64 + lane]);
    // stage full p2 table (768 uint4 = 12288B) into LDS
    const uint4* p2g = p1 + 14 * 64;
    for (int i = tid; i < P2N; i += 256) p2s[i] = p2g[i];
  } else {
    const int i15 = lane & 15, g = lane >> 4;
#pragma unroll
    for (int mt = 0; mt < 7; ++mt)
#pragma unroll
      for (int kt = 0; kt < 2; ++kt) {
        const int d = 16 * mt + i15;
        f16x8 v;
#pragma unroll
        for (int j = 0; j < 8; ++j) {
          const int c = 32 * kt + 8 * g + j;
          v[j] = (half_t)((d < 100 && c < 45) ? isft[d * 45 + c] : 0.f);
        }
        F.a1[mt][kt] = v;
      }
  }

  // zero the activation+scratch buffer (MFMA pad reads must see finite zeros)
  for (int idx = tid; idx < ACTB / 4; idx += 256)
    ((u32*)smem)[idx] = 0u;
  __syncthreads();
  // stage x [4,45] -> rows 0..3 (paired layout)
  if (tid < 192) {
    const int r = tid / 48, c = tid % 48;
    const float v = (c < 45) ? x[b * 180 + r * 45 + c] : 0.f;
    *(half_t*)(smem + (r >> 1) * PRB + c * 4 + (r & 1) * 2) = (half_t)v;
  }
  __syncthreads();

  if constexpr (TW) {
    // L1: w1 -> scratch (non-overlap, 1 barrier); nonlin reads scratch
    sconv_mfma<16, 4, 4, false>(afrB + 0 * 64, smem, lane, wid, 0, 0, SCR);
    nonlin_tiles<TW>(F, p2s, sft, smem, lane, wid, 1, 1, SCR, SCR, E1R, E1R);
    __syncthreads();
    sconv_mfma<32, 16, 16, false>(afrB + 5 * 64, smem, lane, wid, E1R, E1R, 0);
    nonlin_tiles<TW>(F, p2s, sft, smem, lane, wid, 2, 2, 0, 0, E2R, E2R);
    __syncthreads();
    sconv_mfma<64, 32, 32, false>(afrB + 15 * 64, smem, lane, wid, E2R, E2R, 0);
    nonlin_tiles<TW>(F, p2s, sft, smem, lane, wid, 4, 4, 0, 0, E3R, E3R);
    __syncthreads();
    sconv_mfma<128, 64, 64, false>(afrB + 35 * 64, smem, lane, wid, E3R, E3R, 0);
    nonlin_tiles<TW>(F, p2s, sft, smem, lane, wid, 8, 8, 0, 0, 0, 0);
    __syncthreads();
    // L5: w5 (64-row out, overlaps 128-row input) stays INPLACE
    sconv_mfma<64, 128, 128, true>(afrB + 115 * 64, smem, lane, wid, 0, 0, 0);
    nonlin_tiles<TW>(F, p2s, sft, smem, lane, wid, 8, 4, 0, E3R, 0, E3R);
    __syncthreads();
    // L6: w6 -> scratch (G at rows 240..271); d2 -> rows 0..31 + e2-in-place
    sconv_mfma<32, 128, 64, false>(afrB + 195 * 64, smem, lane, wid, 0, E3R, SCR);
    nonlin_tiles<TW>(F, p2s, sft, smem, lane, wid, 4, 2, SCR, E2R, 0, E2R);
    __syncthreads();
    // L7: w7 -> scratch (H at rows 240..255); d3 -> rows 0..15 + e1-in-place
    sconv_mfma<16, 64, 32, false>(afrB + 235 * 64, smem, lane, wid, 0, E2R, SCR);
    nonlin_tiles<TW>(F, p2s, sft, smem, lane, wid, 2, 1, SCR, E1R, 0, E1R);
    __syncthreads();
    // L8: w8 -> scratch; d4 -> rows 0..15
    sconv_mfma<16, 32, 16, false>(afrB + 245 * 64, smem, lane, wid, 0, E1R, SCR);
    nonlin_tiles<TW>(F, p2s, sft, smem, lane, wid, 1, 1, SCR, SCR, 0, 0);
    __syncthreads();
  } else {
    sconv_layer<16, 4, 4, 3, 4>(w1, smem, tid, 0, 0, SCR);
    nonlin_tiles<TW>(F, nullptr, sft, smem, lane, wid, 1, 1, SCR, SCR, E1R, E1R);
    __syncthreads();
    sconv_layer<32, 16, 16, 2, 4>(w2, smem, tid, E1R, E1R, 0);
    nonlin_tiles<TW>(F, nullptr, sft, smem, lane, wid, 2, 2, 0, 0, E2R, E2R);
    __syncthreads();
    sconv_layer<64, 32, 32, 2, 2>(w3, smem, tid, E2R, E2R, 0);
    nonlin_tiles<TW>(F, nullptr, sft, smem, lane, wid, 4, 4, 0, 0, E3R, E3R);
    __syncthreads();
    sconv_layer<128, 64, 64, 2, 1>(w4, smem, tid, E3R, E3R, 0);
    nonlin_tiles<TW>(F, nullptr, sft, smem, lane, wid, 8, 8, 0, 0, 0, 0);
    __syncthreads();
    sconv_layer<64, 128, 128, 2, 2>(w5, smem, tid, 0, 0, 0);  // in-place safe: acc in regs + barrier
    nonlin_tiles<TW>(F, nullptr, sft, smem, lane, wid, 8, 4, 0, E3R, 0, E3R);
    __syncthreads();
    sconv_layer<32, 128, 64, 2, 4>(w6, smem, tid, 0, E3R, SCR);
    nonlin_tiles<TW>(F, nullptr, sft, smem, lane, wid, 4, 2, SCR, E2R, 0, E2R);
    __syncthreads();
    sconv_layer<16, 64, 32, 3, 4>(w7, smem, tid, 0, E2R, SCR);
    nonlin_tiles<TW>(F, nullptr, sft, smem, lane, wid, 2, 1, SCR, E1R, 0, E1R);
    __syncthreads();
    sconv_layer<16, 32, 16, 3, 4>(w8, smem, tid, 0, E1R, SCR);
    nonlin_tiles<TW>(F, nullptr, sft, smem, lane, wid, 1, 1, SCR, SCR, 0, 0);
    __syncthreads();
  }

  // final sconv: O=1, I=16 (d4 rows 0..15) -> out[b,c] fp32
  if (tid < 45) {
    const int c = tid, l = l_of(c);
    float acc = 0.f;
#pragma unroll
    for (int i = 0; i < 16; ++i)
      acc += w9[i * 5 + l] *
             (float)(*(const half_t*)(smem + (i >> 1) * PRB + c * 4 + (i & 1) * 2));
    out[b * 45 + c] = acc * lfac_of(l);
  }
}

extern "C" void kernel_launch(void* const* d_in, const int* in_sizes, int n_in,
                              void* d_out, int out_size, void* d_ws, size_t ws_size,
                              hipStream_t stream) {
  (void)n_in; (void)out_size;
  const float* x    = (const float*)d_in[0];
  const float* sft  = (const float*)d_in[1];
  const float* isft = (const float*)d_in[2];
  const float* w1 = (const float*)d_in[3];
  const float* w2 = (const float*)d_in[4];
  const float* w3 = (const float*)d_in[5];
  const float* w4 = (const float*)d_in[6];
  const float* w5 = (const float*)d_in[7];
  const float* w6 = (const float*)d_in[8];
  const float* w7 = (const float*)d_in[9];
  const float* w8 = (const float*)d_in[10];
  const float* w9 = (const float*)d_in[11];
  float* out = (float*)d_out;

  const int batch = in_sizes[0] / 180;  // 16384

  if (ws_size >= (size_t)WS_NEEDED) {
    u32* wsbuf = (u32*)d_ws;
    const int prepN = WS_FRAG_U32 + WS_AFRAG_U32;
    hipLaunchKernelGGL(scnn_prep, dim3((prepN + 255) / 256), dim3(256), 0, stream,
                       sft, isft, w1, w2, w3, w4, w5, w6, w7, w8, w9, wsbuf);
    hipLaunchKernelGGL((scnn_mfma<true>), dim3(batch), dim3(256), 0, stream,
                       x, sft, isft, w1, w2, w3, w4, w5, w6, w7, w8, w9, wsbuf, out);
  } else {
    hipLaunchKernelGGL((scnn_mfma<false>), dim3(batch), dim3(256), 0, stream,
                       x, sft, isft, w1, w2, w3, w4, w5, w6, w7, w8, w9,
                       (const u32*)nullptr, out);
  }
}